// Round 3
// baseline (77.477 us; speedup 1.0000x reference)
//
#include <hip/hip_runtime.h>

// DilateAttention: q,k,v [B=16, d=32, H=128, W=128] fp32, kernel=3, dilation=2, pad=2.
// Per-pixel 1x9 attention over dilated 3x3 window; OOB taps are zero-padded
// (score 0, value 0) and participate in the softmax denominator.
//
// Key idea this revision: NO predicated loads. Column offsets are clamped to
// always-valid addresses; the (few) garbage accumulations are cancelled once
// per thread by zeroing invalid-tap scores before softmax and invalid-tap
// attention weights before the PV pass. Row (h+-2) validity is wave-uniform.

#define BB 16
#define HD 32
#define HH 128
#define WW 128
#define PLANE (HH * WW)

__global__ __launch_bounds__(256) void dilate_attn_kernel(
    const float* __restrict__ q,
    const float* __restrict__ k,
    const float* __restrict__ v,
    float* __restrict__ out)
{
    const int w     = threadIdx.x & (WW - 1);
    const int rowid = blockIdx.x * 2 + (threadIdx.x >> 7);  // 0..2047
    const int h     = rowid & (HH - 1);
    const int b     = rowid >> 7;

    const size_t base = ((size_t)b * HD) * PLANE + (size_t)h * WW + w;

    // Clamped column deltas: always in-bounds, garbage corrected later.
    const int  dlo = (w >= 2)      ? -2 : -w;            // clamp(w-2, 0) - w
    const int  dhi = (w <= WW - 3) ?  2 : (WW - 1 - w);  // clamp(w+2, 127) - w
    const bool wlo = (w >= 2);
    const bool whi = (w <= WW - 3);
    const bool hlo = (h >= 2);        // wave-uniform
    const bool hhi = (h <= HH - 3);   // wave-uniform

    // ---- Pass 1: scores[n] = sum_d q[d] * k_tap[n][d], unpredicated loads ----
    float s[9];
    #pragma unroll
    for (int n = 0; n < 9; ++n) s[n] = 0.f;

    const float* qp = q + base;
    const float* kp = k + base;

    #pragma unroll 4
    for (int d = 0; d < HD; ++d) {
        const float  qd = qp[(size_t)d * PLANE];
        const float* kc = kp + (size_t)d * PLANE;
        if (hlo) {
            const float* kr = kc - 2 * WW;
            s[0] = fmaf(qd, kr[dlo], s[0]);
            s[1] = fmaf(qd, kr[0],   s[1]);
            s[2] = fmaf(qd, kr[dhi], s[2]);
        }
        s[3] = fmaf(qd, kc[dlo], s[3]);
        s[4] = fmaf(qd, kc[0],   s[4]);
        s[5] = fmaf(qd, kc[dhi], s[5]);
        if (hhi) {
            const float* kr = kc + 2 * WW;
            s[6] = fmaf(qd, kr[dlo], s[6]);
            s[7] = fmaf(qd, kr[0],   s[7]);
            s[8] = fmaf(qd, kr[dhi], s[8]);
        }
    }

    // Cancel garbage from clamped loads: invalid taps have score exactly 0
    // (zero-padded k), and they DO participate in the softmax denominator.
    if (!wlo) { s[0] = 0.f; s[3] = 0.f; s[6] = 0.f; }
    if (!whi) { s[2] = 0.f; s[5] = 0.f; s[8] = 0.f; }
    // h-invalid rows were skipped -> already 0.

    // ---- Softmax over 9 taps ----
    const float scale = 0.17677669529663687f;  // 32^-0.5
    float m = -3.4e38f;
    #pragma unroll
    for (int n = 0; n < 9; ++n) { s[n] *= scale; m = fmaxf(m, s[n]); }
    float sum = 0.f;
    #pragma unroll
    for (int n = 0; n < 9; ++n) { s[n] = __expf(s[n] - m); sum += s[n]; }
    const float inv = 1.f / sum;
    #pragma unroll
    for (int n = 0; n < 9; ++n) s[n] *= inv;

    // Zero attention weights of w-invalid taps (their v is zero-padded in the
    // reference; our clamped loads would otherwise add garbage).
    if (!wlo) { s[0] = 0.f; s[3] = 0.f; s[6] = 0.f; }
    if (!whi) { s[2] = 0.f; s[5] = 0.f; s[8] = 0.f; }

    // ---- Pass 2: out[d] = sum_n attn[n] * v_tap[n][d], unpredicated loads ----
    const float* vp = v + base;
    float*       op = out + base;

    #pragma unroll 4
    for (int d = 0; d < HD; ++d) {
        const float* vc = vp + (size_t)d * PLANE;
        float acc = 0.f;
        if (hlo) {
            const float* vr = vc - 2 * WW;
            acc = fmaf(s[0], vr[dlo], acc);
            acc = fmaf(s[1], vr[0],   acc);
            acc = fmaf(s[2], vr[dhi], acc);
        }
        acc = fmaf(s[3], vc[dlo], acc);
        acc = fmaf(s[4], vc[0],   acc);
        acc = fmaf(s[5], vc[dhi], acc);
        if (hhi) {
            const float* vr = vc + 2 * WW;
            acc = fmaf(s[6], vr[dlo], acc);
            acc = fmaf(s[7], vr[0],   acc);
            acc = fmaf(s[8], vr[dhi], acc);
        }
        op[(size_t)d * PLANE] = acc;
    }
}

extern "C" void kernel_launch(void* const* d_in, const int* in_sizes, int n_in,
                              void* d_out, int out_size, void* d_ws, size_t ws_size,
                              hipStream_t stream) {
    const float* q = (const float*)d_in[0];
    const float* k = (const float*)d_in[1];
    const float* v = (const float*)d_in[2];
    float* out = (float*)d_out;

    // 1 thread per output pixel; block = 2 (b,h) rows; wave = 64 consecutive w.
    dim3 grid(BB * HH / 2);  // 1024
    dim3 block(256);
    dilate_attn_kernel<<<grid, block, 0, stream>>>(q, k, v, out);
}

// Round 4
// 34.308 us; speedup vs baseline: 2.2582x; 2.2582x over previous
//
#include <hip/hip_runtime.h>

// DilateAttention: q,k,v [B=16, d=32, H=128, W=128] fp32, kernel=3, dilation=2, pad=2.
// Per-pixel 1x9 attention over dilated 3x3 window; OOB taps are zero-padded
// (score 0, value 0) and participate in the softmax denominator.
//
// This revision attacks the measured latency-bound regime (VALUBusy 11-24%,
// HBM 14-33%, occupancy ~40%) with:
//  1. Phase-split register loading: per 4-d chunk, issue all 40 loads into a
//     fully-unrolled register array BEFORE any FMA -> ~40 loads in flight per
//     wave (R0-R3 had ~6-8; VGPR_Count 24-32 was the smoking gun).
//  2. XCD-chunk blockIdx swizzle: each of the 8 XCDs owns 256 contiguous
//     (b,h) rows, so the h+-2 tap rows re-read by neighboring blocks hit the
//     LOCAL per-XCD L2 (~200cy) instead of L3/HBM (~900cy).
// Fully branchless: clamped tap addresses, invalid taps cancelled via cndmask.

#define BB 16
#define HD 32
#define HH 128
#define WW 128
#define PLANE (HH * WW)
#define CHUNK 4

__global__ __launch_bounds__(128) void dilate_attn_kernel(
    const float* __restrict__ q,
    const float* __restrict__ k,
    const float* __restrict__ v,
    float* __restrict__ out)
{
    const int w   = threadIdx.x;          // 0..127
    const int bid = blockIdx.x;           // 0..2047
    // XCD swizzle: 2048 blocks / 8 XCDs -> XCD x owns rowids [x*256,(x+1)*256)
    const int rowid = (bid & 7) * 256 + (bid >> 3);
    const int h = rowid & (HH - 1);
    const int b = rowid >> 7;

    const size_t base = ((size_t)b * HD) * PLANE + (size_t)h * WW + w;

    // Clamped tap offsets (always in-bounds). Garbage cancelled after pass 1.
    const int  dlo = (w >= 2)      ? -2      : -w;
    const int  dhi = (w <= WW - 3) ?  2      : (WW - 1 - w);
    const int  rlo = (h >= 2)      ? -2 * WW : 0;   // wave-uniform
    const int  rhi = (h <= HH - 3) ?  2 * WW : 0;   // wave-uniform
    const bool wlo = (w >= 2), whi = (w <= WW - 3);
    const bool hlo = (h >= 2), hhi = (h <= HH - 3);

    int off[9];
    off[0] = rlo + dlo; off[1] = rlo; off[2] = rlo + dhi;
    off[3] = dlo;       off[4] = 0;   off[5] = dhi;
    off[6] = rhi + dlo; off[7] = rhi; off[8] = rhi + dhi;

    const bool tv[9] = { hlo && wlo, hlo, hlo && whi,
                         wlo,        true, whi,
                         hhi && wlo, hhi, hhi && whi };

    // ---- Pass 1: scores. Per 4-d chunk: 40 loads into regs, THEN 36 FMAs ----
    float s[9];
    #pragma unroll
    for (int n = 0; n < 9; ++n) s[n] = 0.f;

    const float* qp = q + base;
    const float* kp = k + base;

    for (int dc = 0; dc < HD; dc += CHUNK) {
        float qreg[CHUNK];
        float kreg[CHUNK][9];
        #pragma unroll
        for (int u = 0; u < CHUNK; ++u) {
            const float* kc = kp + (size_t)(dc + u) * PLANE;
            qreg[u] = qp[(size_t)(dc + u) * PLANE];
            #pragma unroll
            for (int n = 0; n < 9; ++n) kreg[u][n] = kc[off[n]];
        }
        #pragma unroll
        for (int u = 0; u < CHUNK; ++u) {
            #pragma unroll
            for (int n = 0; n < 9; ++n)
                s[n] = fmaf(qreg[u], kreg[u][n], s[n]);
        }
    }

    // Cancel garbage from clamped loads (zero-padded semantics: invalid tap
    // score is exactly 0 and still participates in the softmax denominator).
    #pragma unroll
    for (int n = 0; n < 9; ++n) if (!tv[n]) s[n] = 0.f;

    // ---- Softmax over 9 taps ----
    const float scale = 0.17677669529663687f;  // 32^-0.5
    float m = -3.4e38f;
    #pragma unroll
    for (int n = 0; n < 9; ++n) { s[n] *= scale; m = fmaxf(m, s[n]); }
    float sum = 0.f;
    #pragma unroll
    for (int n = 0; n < 9; ++n) { s[n] = __expf(s[n] - m); sum += s[n]; }
    const float inv = 1.f / sum;
    #pragma unroll
    for (int n = 0; n < 9; ++n) s[n] *= inv;

    // Zero weights of invalid taps (their v is zero-padded in the reference).
    #pragma unroll
    for (int n = 0; n < 9; ++n) if (!tv[n]) s[n] = 0.f;

    // ---- Pass 2: out. Same phase-split structure ----
    const float* vp = v + base;
    float*       op = out + base;

    for (int dc = 0; dc < HD; dc += CHUNK) {
        float vreg[CHUNK][9];
        #pragma unroll
        for (int u = 0; u < CHUNK; ++u) {
            const float* vc = vp + (size_t)(dc + u) * PLANE;
            #pragma unroll
            for (int n = 0; n < 9; ++n) vreg[u][n] = vc[off[n]];
        }
        #pragma unroll
        for (int u = 0; u < CHUNK; ++u) {
            float acc = 0.f;
            #pragma unroll
            for (int n = 0; n < 9; ++n)
                acc = fmaf(s[n], vreg[u][n], acc);
            op[(size_t)(dc + u) * PLANE] = acc;
        }
    }
}

extern "C" void kernel_launch(void* const* d_in, const int* in_sizes, int n_in,
                              void* d_out, int out_size, void* d_ws, size_t ws_size,
                              hipStream_t stream) {
    const float* q = (const float*)d_in[0];
    const float* k = (const float*)d_in[1];
    const float* v = (const float*)d_in[2];
    float* out = (float*)d_out;

    dim3 grid(BB * HH);   // 2048 blocks, one (b,h) row each
    dim3 block(WW);       // 128 threads = 2 waves
    dilate_attn_kernel<<<grid, block, 0, stream>>>(q, k, v, out);
}

// Round 5
// 33.252 us; speedup vs baseline: 2.3300x; 1.0318x over previous
//
#include <hip/hip_runtime.h>

// DilateAttention: q,k,v [B=16, d=32, H=128, W=128] fp32, kernel=3, dilation=2, pad=2.
// Per-pixel 1x9 attention over dilated 3x3 window; OOB taps are zero-padded
// (score 0, value 0) and participate in the softmax denominator.
//
// R5: LDS-staged tiles. Block = (b, 4 h-rows x 128 w), 512 threads, 8 waves.
// k (then v) staged in 4 chunks of 8 d-planes x 8 rows (4 out + 2 halo each
// side) x 128 w = 32 KB, coalesced float4. Tap reads become conflict-free
// ds_read_b32 (~120cy) instead of scattered 4B global loads (200-900cy);
// per-thread VMEM instrs drop ~640 -> ~200. Branchless edges: clamped
// addresses + score/weight cancellation. XCD-chunk swizzle keeps halo
// re-stages in the local per-XCD L2.

#define BB 16
#define HD 32
#define HH 128
#define WW 128
#define PLANE (HH * WW)
#define TH 4            // output rows per block
#define SR 8            // staged rows (TH + 2*2 halo)
#define DC 8            // d-planes per chunk
#define NCH (HD / DC)   // 4 chunks
#define NT 512          // threads per block

__global__ __launch_bounds__(NT) void dilate_attn_kernel(
    const float* __restrict__ q,
    const float* __restrict__ k,
    const float* __restrict__ v,
    float* __restrict__ out)
{
    __shared__ float sm[DC * SR * WW];  // 32 KB

    const int tid = threadIdx.x;
    const int bid = blockIdx.x;                    // 0..511
    const int tile = (bid & 7) * 64 + (bid >> 3);  // XCD swizzle (512 = 8*64)
    const int b  = tile >> 5;                      // 32 tiles per batch
    const int r0 = (tile & 31) * TH;

    const int lr = tid >> 7;          // 0..3 local output row
    const int w  = tid & (WW - 1);    // 0..127

    const size_t bbase = (size_t)b * HD * PLANE;
    const int pix = (r0 + lr) * WW + w;

    // Clamped column deltas (always in-bounds) + tap validity for cancellation.
    const int  dlo = (w >= 2)      ? -2 : -w;
    const int  dhi = (w <= WW - 3) ?  2 : (WW - 1 - w);
    const bool wlo = (w >= 2), whi = (w <= WW - 3);
    const int  h   = r0 + lr;
    const bool hlo = (h >= 2), hhi = (h <= HH - 3);
    const bool tv[9] = { hlo && wlo, hlo, hlo && whi,
                         wlo,        true, whi,
                         hhi && wlo, hhi, hhi && whi };

    // Hoist all 32 q loads (they fly during the first k stage).
    float qreg[HD];
    #pragma unroll
    for (int d = 0; d < HD; ++d)
        qreg[d] = q[bbase + (size_t)d * PLANE + pix];

    float s[9];
    #pragma unroll
    for (int n = 0; n < 9; ++n) s[n] = 0.f;

    // ---- Pass 1: QK scores, 4 chunks of 8 d-planes ----
    for (int c = 0; c < NCH; ++c) {
        {   // stage k chunk: DC planes x SR rows x WW floats, float4-coalesced
            float4 tmp[4];
            int    la[4];
            #pragma unroll
            for (int j = 0; j < 4; ++j) {
                const int i   = tid + j * NT;      // float4 idx 0..2047
                const int u   = i >> 8;            // plane (256 float4/plane)
                const int rem = i & 255;
                const int row = rem >> 5;          // 0..7 (32 float4/row)
                const int w4  = (rem & 31) << 2;
                int gr = r0 - 2 + row;             // clamp; garbage rows only
                gr = gr < 0 ? 0 : (gr > HH - 1 ? HH - 1 : gr);  // feed cancelled taps
                tmp[j] = *(const float4*)(k + bbase + (size_t)(c * DC + u) * PLANE
                                          + (size_t)gr * WW + w4);
                la[j] = u * (SR * WW) + row * WW + w4;
            }
            #pragma unroll
            for (int j = 0; j < 4; ++j)
                *(float4*)(sm + la[j]) = tmp[j];
        }
        __syncthreads();
        #pragma unroll
        for (int u = 0; u < DC; ++u) {
            const float  qd = qreg[c * DC + u];
            const float* rp0 = sm + u * (SR * WW) + lr * WW + w;  // tap rows lr, lr+2, lr+4
            #pragma unroll
            for (int ti = 0; ti < 3; ++ti) {
                const float* rp = rp0 + ti * 2 * WW;
                s[ti * 3 + 0] = fmaf(qd, rp[dlo], s[ti * 3 + 0]);
                s[ti * 3 + 1] = fmaf(qd, rp[0],   s[ti * 3 + 1]);
                s[ti * 3 + 2] = fmaf(qd, rp[dhi], s[ti * 3 + 2]);
            }
        }
        __syncthreads();
    }

    // Cancel garbage (invalid taps: score exactly 0, still in denominator).
    #pragma unroll
    for (int n = 0; n < 9; ++n) if (!tv[n]) s[n] = 0.f;

    // ---- Softmax over 9 taps ----
    const float scale = 0.17677669529663687f;  // 32^-0.5
    float m = -3.4e38f;
    #pragma unroll
    for (int n = 0; n < 9; ++n) { s[n] *= scale; m = fmaxf(m, s[n]); }
    float sum = 0.f;
    #pragma unroll
    for (int n = 0; n < 9; ++n) { s[n] = __expf(s[n] - m); sum += s[n]; }
    const float inv = 1.f / sum;
    #pragma unroll
    for (int n = 0; n < 9; ++n) s[n] *= inv;

    // Zero weights of invalid taps (reference v is zero-padded there).
    #pragma unroll
    for (int n = 0; n < 9; ++n) if (!tv[n]) s[n] = 0.f;

    // ---- Pass 2: PV, same staged structure with v ----
    for (int c = 0; c < NCH; ++c) {
        {   // stage v chunk
            float4 tmp[4];
            int    la[4];
            #pragma unroll
            for (int j = 0; j < 4; ++j) {
                const int i   = tid + j * NT;
                const int u   = i >> 8;
                const int rem = i & 255;
                const int row = rem >> 5;
                const int w4  = (rem & 31) << 2;
                int gr = r0 - 2 + row;
                gr = gr < 0 ? 0 : (gr > HH - 1 ? HH - 1 : gr);
                tmp[j] = *(const float4*)(v + bbase + (size_t)(c * DC + u) * PLANE
                                          + (size_t)gr * WW + w4);
                la[j] = u * (SR * WW) + row * WW + w4;
            }
            #pragma unroll
            for (int j = 0; j < 4; ++j)
                *(float4*)(sm + la[j]) = tmp[j];
        }
        __syncthreads();
        #pragma unroll
        for (int u = 0; u < DC; ++u) {
            const float* rp0 = sm + u * (SR * WW) + lr * WW + w;
            float acc = 0.f;
            #pragma unroll
            for (int ti = 0; ti < 3; ++ti) {
                const float* rp = rp0 + ti * 2 * WW;
                acc = fmaf(s[ti * 3 + 0], rp[dlo], acc);
                acc = fmaf(s[ti * 3 + 1], rp[0],   acc);
                acc = fmaf(s[ti * 3 + 2], rp[dhi], acc);
            }
            out[bbase + (size_t)(c * DC + u) * PLANE + pix] = acc;
        }
        __syncthreads();
    }
}

extern "C" void kernel_launch(void* const* d_in, const int* in_sizes, int n_in,
                              void* d_out, int out_size, void* d_ws, size_t ws_size,
                              hipStream_t stream) {
    const float* q = (const float*)d_in[0];
    const float* k = (const float*)d_in[1];
    const float* v = (const float*)d_in[2];
    float* out = (float*)d_out;

    dim3 grid(BB * HH / TH);  // 512 tiles (b, 4-row strip)
    dim3 block(NT);           // 8 waves
    dilate_attn_kernel<<<grid, block, 0, stream>>>(q, k, v, out);
}